// Round 3
// baseline (334.521 us; speedup 1.0000x reference)
//
#include <hip/hip_runtime.h>
#include <hip/hip_bf16.h>
#include <stdint.h>

#define D_MODEL 1024
#define N_STATE 16
#define BATCH   4
#define SEQ     2048
#define M_ROWS  (BATCH*SEQ)      // 8192
#define H_FFN   (4*D_MODEL)      // 4096
#define NCHUNK  32
#define TCHUNK  (SEQ/NCHUNK)     // 64

typedef __attribute__((ext_vector_type(8))) short short8;
typedef __attribute__((ext_vector_type(4))) float f32x4;

// ---------- helpers ----------
__device__ __forceinline__ unsigned short f2bf(float f) {
  unsigned int u = __builtin_bit_cast(unsigned int, f);
  u += 0x7FFFu + ((u >> 16) & 1u);
  return (unsigned short)(u >> 16);
}

__device__ __forceinline__ void gload_lds16(const void* g, void* l) {
  __builtin_amdgcn_global_load_lds(
      (const __attribute__((address_space(1))) void*)g,
      (__attribute__((address_space(3))) void*)l,
      16, 0, 0);
}

// ---------- fp32 -> bf16 weight conversion ----------
__global__ __launch_bounds__(256)
void cvt_bf16(const float* __restrict__ in, unsigned short* __restrict__ out, int n4) {
  int i = blockIdx.x * 256 + threadIdx.x;
  if (i >= n4) return;
  float4 v = reinterpret_cast<const float4*>(in)[i];
  ushort4 o = { f2bf(v.x), f2bf(v.y), f2bf(v.z), f2bf(v.w) };
  reinterpret_cast<ushort4*>(out)[i] = o;
}

// ---------- LN stats only: per row -> (mu, inv_sigma) ----------
__global__ __launch_bounds__(256)
void ln_stats(const float* __restrict__ in, float2* __restrict__ stats) {
  const int row = blockIdx.x;
  const int tid = threadIdx.x;
  const float4 v = reinterpret_cast<const float4*>(in + (size_t)row * D_MODEL)[tid];
  float s  = v.x + v.y + v.z + v.w;
  float ss = v.x*v.x + v.y*v.y + v.z*v.z + v.w*v.w;
  #pragma unroll
  for (int o = 32; o > 0; o >>= 1) {
    s  += __shfl_down(s, o, 64);
    ss += __shfl_down(ss, o, 64);
  }
  __shared__ float red[8];
  const int wv = tid >> 6;
  if ((tid & 63) == 0) { red[wv] = s; red[4 + wv] = ss; }
  __syncthreads();
  if (tid == 0) {
    s  = red[0] + red[1] + red[2] + red[3];
    ss = red[4] + red[5] + red[6] + red[7];
    const float mu  = s * (1.0f / D_MODEL);
    const float inv = rsqrtf(ss * (1.0f / D_MODEL) - mu * mu + 1e-5f);
    stats[row] = make_float2(mu, inv);
  }
}

// ---------- full LayerNorm (LN2), bf16 out ----------
__global__ __launch_bounds__(256)
void ln_kernel_bf16(const float* __restrict__ in, const float* __restrict__ gamma,
                    const float* __restrict__ beta, unsigned short* __restrict__ outp) {
  const int row = blockIdx.x;
  const int tid = threadIdx.x;
  const float4 v = reinterpret_cast<const float4*>(in + (size_t)row * D_MODEL)[tid];
  float s  = v.x + v.y + v.z + v.w;
  float ss = v.x*v.x + v.y*v.y + v.z*v.z + v.w*v.w;
  #pragma unroll
  for (int o = 32; o > 0; o >>= 1) {
    s  += __shfl_down(s, o, 64);
    ss += __shfl_down(ss, o, 64);
  }
  __shared__ float red[8];
  const int wv = tid >> 6;
  if ((tid & 63) == 0) { red[wv] = s; red[4 + wv] = ss; }
  __syncthreads();
  s  = red[0] + red[1] + red[2] + red[3];
  ss = red[4] + red[5] + red[6] + red[7];
  const float mu  = s * (1.0f / D_MODEL);
  const float inv = rsqrtf(ss * (1.0f / D_MODEL) - mu * mu + 1e-5f);
  const float4 g4 = reinterpret_cast<const float4*>(gamma)[tid];
  const float4 b4 = reinterpret_cast<const float4*>(beta)[tid];
  ushort4 o = { f2bf((v.x - mu) * inv * g4.x + b4.x),
                f2bf((v.y - mu) * inv * g4.y + b4.y),
                f2bf((v.z - mu) * inv * g4.z + b4.z),
                f2bf((v.w - mu) * inv * g4.w + b4.w) };
  reinterpret_cast<ushort4*>(outp + (size_t)row * D_MODEL)[tid] = o;
}

// ---------- SSM scan, chunked (3 phases), LN1 fused via stats ----------
__global__ __launch_bounds__(256)
void scan_phase1(const float* __restrict__ x, const float2* __restrict__ stats,
                 const float* __restrict__ ln_w, const float* __restrict__ ln_b,
                 const float* __restrict__ A_log, const float* __restrict__ B_mat,
                 float* __restrict__ hend) {
  const int d = blockIdx.x * 256 + threadIdx.x;
  const int c = blockIdx.y;
  const int b = blockIdx.z;
  float a[16], Bm[16], h[16];
  const float4* Ar = reinterpret_cast<const float4*>(A_log + d * 16);
  const float4* Br = reinterpret_cast<const float4*>(B_mat + d * 16);
  #pragma unroll
  for (int i = 0; i < 4; i++) {
    const float4 av = Ar[i], bv = Br[i];
    a[4*i+0]=av.x; a[4*i+1]=av.y; a[4*i+2]=av.z; a[4*i+3]=av.w;
    Bm[4*i+0]=bv.x; Bm[4*i+1]=bv.y; Bm[4*i+2]=bv.z; Bm[4*i+3]=bv.w;
  }
  #pragma unroll
  for (int n = 0; n < 16; n++) { a[n] = 1.0f/(1.0f+__expf(-a[n])); h[n] = 0.0f; }
  const float gd = ln_w[d], bd = ln_b[d];

  const float* xp = x + ((size_t)b * SEQ + (size_t)c * TCHUNK) * D_MODEL + d;
  const float2* sp = stats + (size_t)b * SEQ + (size_t)c * TCHUNK;
  #pragma unroll 4
  for (int t = 0; t < TCHUNK; ++t) {
    const float2 st = sp[t];
    const float xv = (xp[(size_t)t * D_MODEL] - st.x) * st.y * gd + bd;
    #pragma unroll
    for (int n = 0; n < 16; n++) h[n] = a[n]*h[n] + Bm[n]*xv;
  }
  float* hp = hend + (((size_t)b * NCHUNK + c) * D_MODEL + d) * 16;
  #pragma unroll
  for (int i = 0; i < 4; i++) {
    float4 o = { h[4*i+0], h[4*i+1], h[4*i+2], h[4*i+3] };
    reinterpret_cast<float4*>(hp)[i] = o;
  }
}

__global__ __launch_bounds__(256)
void scan_phase2(const float* __restrict__ A_log, const float* __restrict__ hend,
                 float* __restrict__ carry) {
  const int idx = blockIdx.x * 256 + threadIdx.x;
  const int n = idx & 15;
  const int d = (idx >> 4) & (D_MODEL - 1);
  const int b = idx >> 14;
  const float a = 1.0f/(1.0f+__expf(-A_log[d*16+n]));
  float aT = a;
  #pragma unroll
  for (int i = 0; i < 6; i++) aT *= aT;   // a^64
  float cv = 0.0f;
  for (int c = 0; c < NCHUNK; c++) {
    const size_t off = (((size_t)b * NCHUNK + c) * D_MODEL + d) * 16 + n;
    carry[off] = cv;
    cv = aT * cv + hend[off];
  }
}

__global__ __launch_bounds__(256)
void scan_phase3(const float* __restrict__ x, const float2* __restrict__ stats,
                 const float* __restrict__ ln_w, const float* __restrict__ ln_b,
                 const float* __restrict__ A_log, const float* __restrict__ B_mat,
                 const float* __restrict__ C_mat, const float* __restrict__ D_vec,
                 const float* __restrict__ carry, unsigned short* __restrict__ ybf) {
  const int d = blockIdx.x * 256 + threadIdx.x;
  const int c = blockIdx.y;
  const int b = blockIdx.z;
  float a[16], Bm[16], Cm[16], h[16];
  const float4* Ar = reinterpret_cast<const float4*>(A_log + d * 16);
  const float4* Br = reinterpret_cast<const float4*>(B_mat + d * 16);
  const float4* Cr = reinterpret_cast<const float4*>(C_mat + d * 16);
  const float4* Hr = reinterpret_cast<const float4*>(carry + (((size_t)b * NCHUNK + c) * D_MODEL + d) * 16);
  #pragma unroll
  for (int i = 0; i < 4; i++) {
    const float4 av = Ar[i], bv = Br[i], cv = Cr[i], hv = Hr[i];
    a[4*i+0]=av.x; a[4*i+1]=av.y; a[4*i+2]=av.z; a[4*i+3]=av.w;
    Bm[4*i+0]=bv.x; Bm[4*i+1]=bv.y; Bm[4*i+2]=bv.z; Bm[4*i+3]=bv.w;
    Cm[4*i+0]=cv.x; Cm[4*i+1]=cv.y; Cm[4*i+2]=cv.z; Cm[4*i+3]=cv.w;
    h[4*i+0]=hv.x; h[4*i+1]=hv.y; h[4*i+2]=hv.z; h[4*i+3]=hv.w;
  }
  #pragma unroll
  for (int n = 0; n < 16; n++) a[n] = 1.0f/(1.0f+__expf(-a[n]));
  const float Dv = D_vec[d];
  const float gd = ln_w[d], bd = ln_b[d];

  const float* xp = x + ((size_t)b * SEQ + (size_t)c * TCHUNK) * D_MODEL + d;
  const float2* sp = stats + (size_t)b * SEQ + (size_t)c * TCHUNK;
  unsigned short* yp = ybf + ((size_t)b * SEQ + (size_t)c * TCHUNK) * D_MODEL + d;
  #pragma unroll 4
  for (int t = 0; t < TCHUNK; ++t) {
    const float2 st = sp[t];
    const float xv = (xp[(size_t)t * D_MODEL] - st.x) * st.y * gd + bd;
    float y = Dv * xv;
    #pragma unroll
    for (int n = 0; n < 16; n++) {
      h[n] = a[n]*h[n] + Bm[n]*xv;
      y += Cm[n]*h[n];
    }
    yp[(size_t)t * D_MODEL] = f2bf(y / (1.0f + __expf(-y)));
  }
}

// ---------- 8-phase bf16 MFMA GEMM (T3+T4+T2+T5+T1) ----------
// C[M,N] = epi(A[M,K] @ Bt[N,K]^T + bias). BM=256, BN in {128,256}, BK=64.
// 512 thr = 8 waves (2M x 4N); per-wave output 128 x BN/4.
// Per K-tile: 4 phases, each {ds_read quadrant | stage parts of t+1 |
// counted vmcnt | s_barrier | lgkmcnt(0)+sched_barrier | setprio MFMA | s_barrier}.
// Stage order per tile: A0,A2 (p0) B0,B1 (p1) [B2,B3|A1] (p2) [A1,A3|A3] (p3).
// Waits: vmcnt(4) at p1 (guarantees Aq1,Aq3 of current tile), vmcnt(2) at p3
// (guarantees needed-at-phase0 set of tile t+1). Never 0 in main loop.
template<int BN, int ACT, bool RES, typename OutT>
__global__ __launch_bounds__(512, 2)
void gemm_8p(const unsigned short* __restrict__ A, const unsigned short* __restrict__ Bt,
             const float* __restrict__ bias, const float* __restrict__ res,
             OutT* __restrict__ C, int M, int N, int K) {
  constexpr int BM = 256, BK = 64;
  constexpr int NR = BN / 64;                 // n-frags per wave: 4 or 2
  constexpr int ASZ = BM * BK;                // elements per A buffer
  constexpr int BSZ = BN * BK;
  __shared__ unsigned short As[2 * ASZ];
  __shared__ unsigned short Bs[2 * BSZ];

  const int tid = threadIdx.x;
  const int l = tid & 63, w = tid >> 6;
  const int wr = w >> 2, wn = w & 3;

  // XCD-aware chunked swizzle (grids are multiples of 8)
  int bid = blockIdx.x;
  const int cpx = gridDim.x >> 3;
  bid = (bid & 7) * cpx + (bid >> 3);
  const int nbx = N / BN;
  const int bn = (bid % nbx) * BN;
  const int bm = (bid / nbx) * BM;

  // staging: per part (64 rows), wave w covers rows 8w..8w+7, lane l ->
  // row +l>>3, LDS byte (l&7)*16 (linear). Source byte pre-swizzled so that
  // LDS[row][kb] = global[row][kb ^ ((row&7)<<4)].
  const int slab = 8 * w + (l >> 3);
  const int skb  = ((l & 7) ^ (l >> 3)) << 4;
  const char* Ag = (const char*)A  + ((size_t)(bm + slab) * K) * 2 + skb;
  const char* Bg = (const char*)Bt + ((size_t)(bn + slab) * K) * 2 + skb;
  char* AsW = (char*)As + (8 * w) * 128;
  char* BsW = (char*)Bs + (8 * w) * 128;

  // read-side: frag addr = base + row*128 + ((kk*64 + (l>>4)*16) ^ ((l&7)<<4))
  const int xk0 = ((l >> 4) * 16) ^ ((l & 7) << 4);
  const int xk1 = (64 + (l >> 4) * 16) ^ ((l & 7) << 4);
  const char* Ar = (const char*)As + (wr * 128 + (l & 15)) * 128;
  const char* Br = (const char*)Bs + (wn * (BN / 4) + (l & 15)) * 128;

  f32x4 acc[8][NR] = {};
  short8 bf[NR][2];

#define STA(buf, q, k0) gload_lds16(Ag + ((size_t)(q)*64*K + (k0))*2, AsW + (buf)*(ASZ*2) + (q)*8192)
#define STB(buf, q, k0) gload_lds16(Bg + ((size_t)(q)*64*K + (k0))*2, BsW + (buf)*(BSZ*2) + (q)*8192)

#define PHASE(P, CB, STAGES, WAITS)                                              \
  {                                                                              \
    const char* Ap = Ar + (CB) * (ASZ * 2);                                      \
    if ((P) == 0) {                                                              \
      const char* Bp = Br + (CB) * (BSZ * 2);                                    \
      _Pragma("unroll")                                                          \
      for (int nf = 0; nf < NR; ++nf) {                                          \
        bf[nf][0] = *reinterpret_cast<const short8*>(Bp + nf * 2048 + xk0);      \
        bf[nf][1] = *reinterpret_cast<const short8*>(Bp + nf * 2048 + xk1);      \
      }                                                                          \
    }                                                                            \
    short8 fa00 = *reinterpret_cast<const short8*>(Ap + (2*(P)  ) * 2048 + xk0); \
    short8 fa01 = *reinterpret_cast<const short8*>(Ap + (2*(P)  ) * 2048 + xk1); \
    short8 fa10 = *reinterpret_cast<const short8*>(Ap + (2*(P)+1) * 2048 + xk0); \
    short8 fa11 = *reinterpret_cast<const short8*>(Ap + (2*(P)+1) * 2048 + xk1); \
    STAGES;                                                                      \
    WAITS;                                                                       \
    __builtin_amdgcn_s_barrier();                                                \
    asm volatile("s_waitcnt lgkmcnt(0)" ::: "memory");                           \
    __builtin_amdgcn_sched_barrier(0);                                           \
    __builtin_amdgcn_s_setprio(1);                                               \
    _Pragma("unroll")                                                            \
    for (int nf = 0; nf < NR; ++nf) {                                            \
      acc[2*(P)  ][nf] = __builtin_amdgcn_mfma_f32_16x16x32_bf16(fa00, bf[nf][0], acc[2*(P)  ][nf], 0,0,0); \
      acc[2*(P)  ][nf] = __builtin_amdgcn_mfma_f32_16x16x32_bf16(fa01, bf[nf][1], acc[2*(P)  ][nf], 0,0,0); \
      acc[2*(P)+1][nf] = __builtin_amdgcn_mfma_f32_16x16x32_bf16(fa10, bf[nf][0], acc[2*(P)+1][nf], 0,0,0); \
      acc[2*(P)+1][nf] = __builtin_amdgcn_mfma_f32_16x16x32_bf16(fa11, bf[nf][1], acc[2*(P)+1][nf], 0,0,0); \
    }                                                                            \
    __builtin_amdgcn_s_setprio(0);                                               \
    __builtin_amdgcn_s_barrier();                                                \
  }

  // prologue: tile 0 -> buf 0, needed-at-phase0 parts first
  STA(0, 0, 0); STA(0, 2, 0);
  STB(0, 0, 0); STB(0, 1, 0);
  if constexpr (NR == 4) { STB(0, 2, 0); STB(0, 3, 0); }
  STA(0, 1, 0); STA(0, 3, 0);
  asm volatile("s_waitcnt vmcnt(2)" ::: "memory");
  __builtin_amdgcn_s_barrier();

  const int NT = K / BK;
  for (int t = 0; t < NT - 1; ++t) {
    const int cb = t & 1, nb2 = cb ^ 1;
    const int kn = (t + 1) * BK;
    if constexpr (NR == 4) {
      PHASE(0, cb, { STA(nb2,0,kn); STA(nb2,2,kn); }, ((void)0))
      PHASE(1, cb, { STB(nb2,0,kn); STB(nb2,1,kn); },
            asm volatile("s_waitcnt vmcnt(4)" ::: "memory"))
      PHASE(2, cb, { STB(nb2,2,kn); STB(nb2,3,kn); }, ((void)0))
      PHASE(3, cb, { STA(nb2,1,kn); STA(nb2,3,kn); },
            asm volatile("s_waitcnt vmcnt(2)" ::: "memory"))
    } else {
      PHASE(0, cb, { STA(nb2,0,kn); STA(nb2,2,kn); }, ((void)0))
      PHASE(1, cb, { STB(nb2,0,kn); STB(nb2,1,kn); },
            asm volatile("s_waitcnt vmcnt(4)" ::: "memory"))
      PHASE(2, cb, { STA(nb2,1,kn); }, ((void)0))
      PHASE(3, cb, { STA(nb2,3,kn); },
            asm volatile("s_waitcnt vmcnt(2)" ::: "memory"))
    }
  }
  // epilogue tile (no staging; drain remaining A parts before phase 2)
  {
    const int cb = (NT - 1) & 1;
    PHASE(0, cb, ((void)0), ((void)0))
    PHASE(1, cb, ((void)0), asm volatile("s_waitcnt vmcnt(0)" ::: "memory"))
    PHASE(2, cb, ((void)0), ((void)0))
    PHASE(3, cb, ((void)0), ((void)0))
  }
#undef PHASE
#undef STA
#undef STB

  // epilogue: D row=(l>>4)*4+r, col=l&15
  const int fr = (l >> 4) * 4;
  const int fc = l & 15;
  #pragma unroll
  for (int n = 0; n < NR; ++n) {
    const int col = bn + wn * (BN / 4) + n * 16 + fc;
    const float bv = bias[col];
    #pragma unroll
    for (int m = 0; m < 8; ++m) {
      const int row0 = bm + wr * 128 + m * 16 + fr;
      #pragma unroll
      for (int r = 0; r < 4; ++r) {
        const size_t idx = (size_t)(row0 + r) * N + col;
        float v = acc[m][n][r] + bv;
        if (ACT == 1) v = 0.5f * v * (1.0f + erff(v * 0.70710678118f));
        if (RES) v += res[idx];
        if constexpr (sizeof(OutT) == 2) C[idx] = (OutT)f2bf(v);
        else                             C[idx] = v;
      }
    }
  }
}

// ---------- launch ----------
extern "C" void kernel_launch(void* const* d_in, const int* in_sizes, int n_in,
                              void* d_out, int out_size, void* d_ws, size_t ws_size,
                              hipStream_t stream) {
  const float* x      = (const float*)d_in[0];
  const float* ln_w   = (const float*)d_in[1];
  const float* ln_b   = (const float*)d_in[2];
  const float* A_log  = (const float*)d_in[3];
  const float* B_mat  = (const float*)d_in[4];
  const float* C_mat  = (const float*)d_in[5];
  const float* D_vec  = (const float*)d_in[6];
  const float* out_w  = (const float*)d_in[7];
  const float* out_b  = (const float*)d_in[8];
  const float* ln2_w  = (const float*)d_in[9];
  const float* ln2_b  = (const float*)d_in[10];
  const float* ffn1_w = (const float*)d_in[11];
  const float* ffn1_b = (const float*)d_in[12];
  const float* ffn2_w = (const float*)d_in[13];
  const float* ffn2_b = (const float*)d_in[14];
  float* out = (float*)d_out;

  char* ws = (char*)d_ws;
  const size_t MB = 1u << 20;
  float*          x1    = (float*)(ws);                    // 32MB (GEMM1 out)
  unsigned short* ybf   = (unsigned short*)(ws + 32*MB);   // 16MB; reused as xn2
  unsigned short* hdn   = (unsigned short*)(ws + 48*MB);   // 64MB
  unsigned short* w1b   = (unsigned short*)(ws + 112*MB);  // 2MB
  unsigned short* w2b   = (unsigned short*)(ws + 114*MB);  // 8MB
  unsigned short* w3b   = (unsigned short*)(ws + 122*MB);  // 8MB
  float*          hend  = (float*)(ws + 130*MB);           // 8MB
  float*          carry = (float*)(ws + 138*MB);           // 8MB
  float2*         stats = (float2*)(ws + 146*MB);          // 64KB

  // weights -> bf16
  cvt_bf16<<<(D_MODEL*D_MODEL/4)/256, 256, 0, stream>>>(out_w,  w1b, D_MODEL*D_MODEL/4);
  cvt_bf16<<<(H_FFN*D_MODEL/4)/256,  256, 0, stream>>>(ffn1_w, w2b, H_FFN*D_MODEL/4);
  cvt_bf16<<<(H_FFN*D_MODEL/4)/256,  256, 0, stream>>>(ffn2_w, w3b, H_FFN*D_MODEL/4);

  // LN1 stats (normalize fused into scan)
  ln_stats<<<M_ROWS, 256, 0, stream>>>(x, stats);

  // SSM scan -> ybf = silu(y) bf16
  dim3 gscan(D_MODEL/256, NCHUNK, BATCH);
  scan_phase1<<<gscan, 256, 0, stream>>>(x, stats, ln_w, ln_b, A_log, B_mat, hend);
  scan_phase2<<<(BATCH*D_MODEL*N_STATE)/256, 256, 0, stream>>>(A_log, hend, carry);
  scan_phase3<<<gscan, 256, 0, stream>>>(x, stats, ln_w, ln_b, A_log, B_mat, C_mat,
                                         D_vec, carry, ybf);

  // GEMM1: x1 = x + silu_y @ out_w^T + out_b   (BN=128: grid 256)
  gemm_8p<128, 0, true, float><<<dim3((M_ROWS/256)*(D_MODEL/128)), 512, 0, stream>>>(
      ybf, w1b, out_b, x, x1, M_ROWS, D_MODEL, D_MODEL);

  // LN2: xn2 = LN(x1) bf16 (into ybf buffer)
  ln_kernel_bf16<<<M_ROWS, 256, 0, stream>>>(x1, ln2_w, ln2_b, ybf);

  // GEMM2: hdn = gelu(xn2 @ ffn1^T + ffn1_b) bf16  (BN=256: grid 512)
  gemm_8p<256, 1, false, unsigned short><<<dim3((M_ROWS/256)*(H_FFN/256)), 512, 0, stream>>>(
      ybf, w2b, ffn1_b, nullptr, hdn, M_ROWS, H_FFN, D_MODEL);

  // GEMM3: out = x1 + hdn @ ffn2^T + ffn2_b (BN=128: grid 256)
  gemm_8p<128, 0, true, float><<<dim3((M_ROWS/256)*(D_MODEL/128)), 512, 0, stream>>>(
      hdn, w3b, ffn2_b, x1, out, M_ROWS, D_MODEL, H_FFN);
}

// Round 4
// 331.625 us; speedup vs baseline: 1.0087x; 1.0087x over previous
//
#include <hip/hip_runtime.h>
#include <hip/hip_bf16.h>
#include <stdint.h>

#define D_MODEL 1024
#define N_STATE 16
#define BATCH   4
#define SEQ     2048
#define M_ROWS  (BATCH*SEQ)      // 8192
#define H_FFN   (4*D_MODEL)      // 4096
#define NCHUNK  32
#define TCHUNK  (SEQ/NCHUNK)     // 64

typedef __attribute__((ext_vector_type(8))) short short8;
typedef __attribute__((ext_vector_type(4))) float f32x4;

// ---------- helpers ----------
__device__ __forceinline__ unsigned short f2bf(float f) {
  unsigned int u = __builtin_bit_cast(unsigned int, f);
  u += 0x7FFFu + ((u >> 16) & 1u);
  return (unsigned short)(u >> 16);
}

__device__ __forceinline__ void gload_lds16(const void* g, void* l) {
  __builtin_amdgcn_global_load_lds(
      (const __attribute__((address_space(1))) void*)g,
      (__attribute__((address_space(3))) void*)l,
      16, 0, 0);
}

// ---------- fp32 -> bf16 weight conversion ----------
__global__ __launch_bounds__(256)
void cvt_bf16(const float* __restrict__ in, unsigned short* __restrict__ out, int n4) {
  int i = blockIdx.x * 256 + threadIdx.x;
  if (i >= n4) return;
  float4 v = reinterpret_cast<const float4*>(in)[i];
  ushort4 o = { f2bf(v.x), f2bf(v.y), f2bf(v.z), f2bf(v.w) };
  reinterpret_cast<ushort4*>(out)[i] = o;
}

// ---------- LN stats only: per row -> (mu, inv_sigma) ----------
__global__ __launch_bounds__(256)
void ln_stats(const float* __restrict__ in, float2* __restrict__ stats) {
  const int row = blockIdx.x;
  const int tid = threadIdx.x;
  const float4 v = reinterpret_cast<const float4*>(in + (size_t)row * D_MODEL)[tid];
  float s  = v.x + v.y + v.z + v.w;
  float ss = v.x*v.x + v.y*v.y + v.z*v.z + v.w*v.w;
  #pragma unroll
  for (int o = 32; o > 0; o >>= 1) {
    s  += __shfl_down(s, o, 64);
    ss += __shfl_down(ss, o, 64);
  }
  __shared__ float red[8];
  const int wv = tid >> 6;
  if ((tid & 63) == 0) { red[wv] = s; red[4 + wv] = ss; }
  __syncthreads();
  if (tid == 0) {
    s  = red[0] + red[1] + red[2] + red[3];
    ss = red[4] + red[5] + red[6] + red[7];
    const float mu  = s * (1.0f / D_MODEL);
    const float inv = rsqrtf(ss * (1.0f / D_MODEL) - mu * mu + 1e-5f);
    stats[row] = make_float2(mu, inv);
  }
}

// ---------- full LayerNorm (LN2), bf16 out ----------
__global__ __launch_bounds__(256)
void ln_kernel_bf16(const float* __restrict__ in, const float* __restrict__ gamma,
                    const float* __restrict__ beta, unsigned short* __restrict__ outp) {
  const int row = blockIdx.x;
  const int tid = threadIdx.x;
  const float4 v = reinterpret_cast<const float4*>(in + (size_t)row * D_MODEL)[tid];
  float s  = v.x + v.y + v.z + v.w;
  float ss = v.x*v.x + v.y*v.y + v.z*v.z + v.w*v.w;
  #pragma unroll
  for (int o = 32; o > 0; o >>= 1) {
    s  += __shfl_down(s, o, 64);
    ss += __shfl_down(ss, o, 64);
  }
  __shared__ float red[8];
  const int wv = tid >> 6;
  if ((tid & 63) == 0) { red[wv] = s; red[4 + wv] = ss; }
  __syncthreads();
  s  = red[0] + red[1] + red[2] + red[3];
  ss = red[4] + red[5] + red[6] + red[7];
  const float mu  = s * (1.0f / D_MODEL);
  const float inv = rsqrtf(ss * (1.0f / D_MODEL) - mu * mu + 1e-5f);
  const float4 g4 = reinterpret_cast<const float4*>(gamma)[tid];
  const float4 b4 = reinterpret_cast<const float4*>(beta)[tid];
  ushort4 o = { f2bf((v.x - mu) * inv * g4.x + b4.x),
                f2bf((v.y - mu) * inv * g4.y + b4.y),
                f2bf((v.z - mu) * inv * g4.z + b4.z),
                f2bf((v.w - mu) * inv * g4.w + b4.w) };
  reinterpret_cast<ushort4*>(outp + (size_t)row * D_MODEL)[tid] = o;
}

// ---------- SSM scan, chunked (3 phases), LN1 fused via stats ----------
__global__ __launch_bounds__(256)
void scan_phase1(const float* __restrict__ x, const float2* __restrict__ stats,
                 const float* __restrict__ ln_w, const float* __restrict__ ln_b,
                 const float* __restrict__ A_log, const float* __restrict__ B_mat,
                 float* __restrict__ hend) {
  const int d = blockIdx.x * 256 + threadIdx.x;
  const int c = blockIdx.y;
  const int b = blockIdx.z;
  float a[16], Bm[16], h[16];
  const float4* Ar = reinterpret_cast<const float4*>(A_log + d * 16);
  const float4* Br = reinterpret_cast<const float4*>(B_mat + d * 16);
  #pragma unroll
  for (int i = 0; i < 4; i++) {
    const float4 av = Ar[i], bv = Br[i];
    a[4*i+0]=av.x; a[4*i+1]=av.y; a[4*i+2]=av.z; a[4*i+3]=av.w;
    Bm[4*i+0]=bv.x; Bm[4*i+1]=bv.y; Bm[4*i+2]=bv.z; Bm[4*i+3]=bv.w;
  }
  #pragma unroll
  for (int n = 0; n < 16; n++) { a[n] = 1.0f/(1.0f+__expf(-a[n])); h[n] = 0.0f; }
  const float gd = ln_w[d], bd = ln_b[d];

  const float* xp = x + ((size_t)b * SEQ + (size_t)c * TCHUNK) * D_MODEL + d;
  const float2* sp = stats + (size_t)b * SEQ + (size_t)c * TCHUNK;
  #pragma unroll 4
  for (int t = 0; t < TCHUNK; ++t) {
    const float2 st = sp[t];
    const float xv = (xp[(size_t)t * D_MODEL] - st.x) * st.y * gd + bd;
    #pragma unroll
    for (int n = 0; n < 16; n++) h[n] = a[n]*h[n] + Bm[n]*xv;
  }
  float* hp = hend + (((size_t)b * NCHUNK + c) * D_MODEL + d) * 16;
  #pragma unroll
  for (int i = 0; i < 4; i++) {
    float4 o = { h[4*i+0], h[4*i+1], h[4*i+2], h[4*i+3] };
    reinterpret_cast<float4*>(hp)[i] = o;
  }
}

__global__ __launch_bounds__(256)
void scan_phase2(const float* __restrict__ A_log, const float* __restrict__ hend,
                 float* __restrict__ carry) {
  const int idx = blockIdx.x * 256 + threadIdx.x;
  const int n = idx & 15;
  const int d = (idx >> 4) & (D_MODEL - 1);
  const int b = idx >> 14;
  const float a = 1.0f/(1.0f+__expf(-A_log[d*16+n]));
  float aT = a;
  #pragma unroll
  for (int i = 0; i < 6; i++) aT *= aT;   // a^64
  float cv = 0.0f;
  for (int c = 0; c < NCHUNK; c++) {
    const size_t off = (((size_t)b * NCHUNK + c) * D_MODEL + d) * 16 + n;
    carry[off] = cv;
    cv = aT * cv + hend[off];
  }
}

__global__ __launch_bounds__(256)
void scan_phase3(const float* __restrict__ x, const float2* __restrict__ stats,
                 const float* __restrict__ ln_w, const float* __restrict__ ln_b,
                 const float* __restrict__ A_log, const float* __restrict__ B_mat,
                 const float* __restrict__ C_mat, const float* __restrict__ D_vec,
                 const float* __restrict__ carry, unsigned short* __restrict__ ybf) {
  const int d = blockIdx.x * 256 + threadIdx.x;
  const int c = blockIdx.y;
  const int b = blockIdx.z;
  float a[16], Bm[16], Cm[16], h[16];
  const float4* Ar = reinterpret_cast<const float4*>(A_log + d * 16);
  const float4* Br = reinterpret_cast<const float4*>(B_mat + d * 16);
  const float4* Cr = reinterpret_cast<const float4*>(C_mat + d * 16);
  const float4* Hr = reinterpret_cast<const float4*>(carry + (((size_t)b * NCHUNK + c) * D_MODEL + d) * 16);
  #pragma unroll
  for (int i = 0; i < 4; i++) {
    const float4 av = Ar[i], bv = Br[i], cv = Cr[i], hv = Hr[i];
    a[4*i+0]=av.x; a[4*i+1]=av.y; a[4*i+2]=av.z; a[4*i+3]=av.w;
    Bm[4*i+0]=bv.x; Bm[4*i+1]=bv.y; Bm[4*i+2]=bv.z; Bm[4*i+3]=bv.w;
    Cm[4*i+0]=cv.x; Cm[4*i+1]=cv.y; Cm[4*i+2]=cv.z; Cm[4*i+3]=cv.w;
    h[4*i+0]=hv.x; h[4*i+1]=hv.y; h[4*i+2]=hv.z; h[4*i+3]=hv.w;
  }
  #pragma unroll
  for (int n = 0; n < 16; n++) a[n] = 1.0f/(1.0f+__expf(-a[n]));
  const float Dv = D_vec[d];
  const float gd = ln_w[d], bd = ln_b[d];

  const float* xp = x + ((size_t)b * SEQ + (size_t)c * TCHUNK) * D_MODEL + d;
  const float2* sp = stats + (size_t)b * SEQ + (size_t)c * TCHUNK;
  unsigned short* yp = ybf + ((size_t)b * SEQ + (size_t)c * TCHUNK) * D_MODEL + d;
  #pragma unroll 4
  for (int t = 0; t < TCHUNK; ++t) {
    const float2 st = sp[t];
    const float xv = (xp[(size_t)t * D_MODEL] - st.x) * st.y * gd + bd;
    float y = Dv * xv;
    #pragma unroll
    for (int n = 0; n < 16; n++) {
      h[n] = a[n]*h[n] + Bm[n]*xv;
      y += Cm[n]*h[n];
    }
    yp[(size_t)t * D_MODEL] = f2bf(y / (1.0f + __expf(-y)));
  }
}

// ---------- 8-phase bf16 MFMA GEMM (T3+T4+T2+T5+T1) ----------
// K-loop identical to R3 (verified correct). Epilogue rewritten: stage each
// 16xWCOLS fragment through a wave-private padded LDS slab, then write full
// contiguous float4/ushort4 lines (and read residual coalesced).
template<int BN, int ACT, bool RES, typename OutT>
__global__ __launch_bounds__(512, 2)
void gemm_8p(const unsigned short* __restrict__ A, const unsigned short* __restrict__ Bt,
             const float* __restrict__ bias, const float* __restrict__ res,
             OutT* __restrict__ C, int M, int N, int K) {
  constexpr int BM = 256, BK = 64;
  constexpr int NR = BN / 64;                 // n-frags per wave: 4 or 2
  constexpr int ASZ = BM * BK;                // elements per A buffer
  constexpr int BSZ = BN * BK;
  __shared__ unsigned short As[2 * ASZ];
  __shared__ unsigned short Bs[2 * BSZ];

  const int tid = threadIdx.x;
  const int l = tid & 63, w = tid >> 6;
  const int wr = w >> 2, wn = w & 3;

  // XCD-aware chunked swizzle (grids are multiples of 8)
  int bid = blockIdx.x;
  const int cpx = gridDim.x >> 3;
  bid = (bid & 7) * cpx + (bid >> 3);
  const int nbx = N / BN;
  const int bn = (bid % nbx) * BN;
  const int bm = (bid / nbx) * BM;

  // staging: per part (64 rows), wave w covers rows 8w..8w+7, lane l ->
  // row +l>>3, LDS byte (l&7)*16 (linear). Source byte pre-swizzled so that
  // LDS[row][kb] = global[row][kb ^ ((row&7)<<4)].
  const int slab8 = 8 * w + (l >> 3);
  const int skb  = ((l & 7) ^ (l >> 3)) << 4;
  const char* Ag = (const char*)A  + ((size_t)(bm + slab8) * K) * 2 + skb;
  const char* Bg = (const char*)Bt + ((size_t)(bn + slab8) * K) * 2 + skb;
  char* AsW = (char*)As + (8 * w) * 128;
  char* BsW = (char*)Bs + (8 * w) * 128;

  // read-side: frag addr = base + row*128 + ((kk*64 + (l>>4)*16) ^ ((l&7)<<4))
  const int xk0 = ((l >> 4) * 16) ^ ((l & 7) << 4);
  const int xk1 = (64 + (l >> 4) * 16) ^ ((l & 7) << 4);
  const char* Ar = (const char*)As + (wr * 128 + (l & 15)) * 128;
  const char* Br = (const char*)Bs + (wn * (BN / 4) + (l & 15)) * 128;

  f32x4 acc[8][NR] = {};
  short8 bf[NR][2];

#define STA(buf, q, k0) gload_lds16(Ag + ((size_t)(q)*64*K + (k0))*2, AsW + (buf)*(ASZ*2) + (q)*8192)
#define STB(buf, q, k0) gload_lds16(Bg + ((size_t)(q)*64*K + (k0))*2, BsW + (buf)*(BSZ*2) + (q)*8192)

#define PHASE(P, CB, STAGES, WAITS)                                              \
  {                                                                              \
    const char* Ap = Ar + (CB) * (ASZ * 2);                                      \
    if ((P) == 0) {                                                              \
      const char* Bp = Br + (CB) * (BSZ * 2);                                    \
      _Pragma("unroll")                                                          \
      for (int nf = 0; nf < NR; ++nf) {                                          \
        bf[nf][0] = *reinterpret_cast<const short8*>(Bp + nf * 2048 + xk0);      \
        bf[nf][1] = *reinterpret_cast<const short8*>(Bp + nf * 2048 + xk1);      \
      }                                                                          \
    }                                                                            \
    short8 fa00 = *reinterpret_cast<const short8*>(Ap + (2*(P)  ) * 2048 + xk0); \
    short8 fa01 = *reinterpret_cast<const short8*>(Ap + (2*(P)  ) * 2048 + xk1); \
    short8 fa10 = *reinterpret_cast<const short8*>(Ap + (2*(P)+1) * 2048 + xk0); \
    short8 fa11 = *reinterpret_cast<const short8*>(Ap + (2*(P)+1) * 2048 + xk1); \
    STAGES;                                                                      \
    WAITS;                                                                       \
    __builtin_amdgcn_s_barrier();                                                \
    asm volatile("s_waitcnt lgkmcnt(0)" ::: "memory");                           \
    __builtin_amdgcn_sched_barrier(0);                                           \
    __builtin_amdgcn_s_setprio(1);                                               \
    _Pragma("unroll")                                                            \
    for (int nf = 0; nf < NR; ++nf) {                                            \
      acc[2*(P)  ][nf] = __builtin_amdgcn_mfma_f32_16x16x32_bf16(fa00, bf[nf][0], acc[2*(P)  ][nf], 0,0,0); \
      acc[2*(P)  ][nf] = __builtin_amdgcn_mfma_f32_16x16x32_bf16(fa01, bf[nf][1], acc[2*(P)  ][nf], 0,0,0); \
      acc[2*(P)+1][nf] = __builtin_amdgcn_mfma_f32_16x16x32_bf16(fa10, bf[nf][0], acc[2*(P)+1][nf], 0,0,0); \
      acc[2*(P)+1][nf] = __builtin_amdgcn_mfma_f32_16x16x32_bf16(fa11, bf[nf][1], acc[2*(P)+1][nf], 0,0,0); \
    }                                                                            \
    __builtin_amdgcn_s_setprio(0);                                               \
    __builtin_amdgcn_s_barrier();                                                \
  }

  // prologue: tile 0 -> buf 0, needed-at-phase0 parts first
  STA(0, 0, 0); STA(0, 2, 0);
  STB(0, 0, 0); STB(0, 1, 0);
  if constexpr (NR == 4) { STB(0, 2, 0); STB(0, 3, 0); }
  STA(0, 1, 0); STA(0, 3, 0);
  asm volatile("s_waitcnt vmcnt(2)" ::: "memory");
  __builtin_amdgcn_s_barrier();

  const int NT = K / BK;
  for (int t = 0; t < NT - 1; ++t) {
    const int cb = t & 1, nb2 = cb ^ 1;
    const int kn = (t + 1) * BK;
    if constexpr (NR == 4) {
      PHASE(0, cb, { STA(nb2,0,kn); STA(nb2,2,kn); }, ((void)0))
      PHASE(1, cb, { STB(nb2,0,kn); STB(nb2,1,kn); },
            asm volatile("s_waitcnt vmcnt(4)" ::: "memory"))
      PHASE(2, cb, { STB(nb2,2,kn); STB(nb2,3,kn); }, ((void)0))
      PHASE(3, cb, { STA(nb2,1,kn); STA(nb2,3,kn); },
            asm volatile("s_waitcnt vmcnt(2)" ::: "memory"))
    } else {
      PHASE(0, cb, { STA(nb2,0,kn); STA(nb2,2,kn); }, ((void)0))
      PHASE(1, cb, { STB(nb2,0,kn); STB(nb2,1,kn); },
            asm volatile("s_waitcnt vmcnt(4)" ::: "memory"))
      PHASE(2, cb, { STA(nb2,1,kn); }, ((void)0))
      PHASE(3, cb, { STA(nb2,3,kn); },
            asm volatile("s_waitcnt vmcnt(2)" ::: "memory"))
    }
  }
  // epilogue tile (no staging)
  {
    const int cb = (NT - 1) & 1;
    PHASE(0, cb, ((void)0), ((void)0))
    PHASE(1, cb, ((void)0), asm volatile("s_waitcnt vmcnt(0)" ::: "memory"))
    PHASE(2, cb, ((void)0), ((void)0))
    PHASE(3, cb, ((void)0), ((void)0))
  }
#undef PHASE
#undef STA
#undef STB

  // ---- coalesced epilogue via wave-private LDS slab ----
  // After the final PHASE's trailing s_barrier, every wave has consumed all
  // its LDS K-data into registers, so As may be reused without further sync.
  constexpr int WCOLS = NR * 16;            // 64 (NR=4) or 32 (NR=2)
  constexpr int LPAD  = WCOLS + 1;          // +1 float pad: conflict-free ds_write
  constexpr int CPR   = WCOLS / 4;          // float4 chunks per row
  constexpr int RPP   = 64 / CPR;           // rows per readback pass
  float* slab = (float*)((char*)As + w * 8192);   // 8 waves x 8KB = 64KB = sizeof(As)
  const int fr = (l >> 4) * 4;
  const int fc = l & 15;
  const int rdrow = l / CPR;
  const int rdchk = l % CPR;
  const int colg0 = bn + wn * WCOLS;
  float bvn[NR];
  #pragma unroll
  for (int n = 0; n < NR; ++n) bvn[n] = bias[colg0 + n * 16 + fc];

  #pragma unroll
  for (int m = 0; m < 8; ++m) {
    asm volatile("s_waitcnt lgkmcnt(0)" ::: "memory");  // prev readback done
    #pragma unroll
    for (int n = 0; n < NR; ++n)
      #pragma unroll
      for (int r = 0; r < 4; ++r)
        slab[(fr + r) * LPAD + n * 16 + fc] = acc[m][n][r] + bvn[n];
    asm volatile("s_waitcnt lgkmcnt(0)" ::: "memory");  // writes visible to wave
    const int row0 = bm + wr * 128 + m * 16;
    #pragma unroll
    for (int p = 0; p < 16 / RPP; ++p) {
      const int row = p * RPP + rdrow;
      float4 v4 = *reinterpret_cast<const float4*>(&slab[row * LPAD + rdchk * 4]);
      const size_t idx = (size_t)(row0 + row) * N + colg0 + rdchk * 4;
      float vv[4] = { v4.x, v4.y, v4.z, v4.w };
      if (ACT == 1) {
        #pragma unroll
        for (int j = 0; j < 4; ++j)
          vv[j] = 0.5f * vv[j] * (1.0f + erff(vv[j] * 0.70710678118f));
      }
      if (RES) {
        const float4 r4 = *reinterpret_cast<const float4*>(&res[idx]);
        vv[0] += r4.x; vv[1] += r4.y; vv[2] += r4.z; vv[3] += r4.w;
      }
      if constexpr (sizeof(OutT) == 2) {
        ushort4 o = { f2bf(vv[0]), f2bf(vv[1]), f2bf(vv[2]), f2bf(vv[3]) };
        *reinterpret_cast<ushort4*>(&C[idx]) = o;
      } else {
        float4 o = { vv[0], vv[1], vv[2], vv[3] };
        *reinterpret_cast<float4*>(&C[idx]) = o;
      }
    }
  }
}

// ---------- launch ----------
extern "C" void kernel_launch(void* const* d_in, const int* in_sizes, int n_in,
                              void* d_out, int out_size, void* d_ws, size_t ws_size,
                              hipStream_t stream) {
  const float* x      = (const float*)d_in[0];
  const float* ln_w   = (const float*)d_in[1];
  const float* ln_b   = (const float*)d_in[2];
  const float* A_log  = (const float*)d_in[3];
  const float* B_mat  = (const float*)d_in[4];
  const float* C_mat  = (const float*)d_in[5];
  const float* D_vec  = (const float*)d_in[6];
  const float* out_w  = (const float*)d_in[7];
  const float* out_b  = (const float*)d_in[8];
  const float* ln2_w  = (const float*)d_in[9];
  const float* ln2_b  = (const float*)d_in[10];
  const float* ffn1_w = (const float*)d_in[11];
  const float* ffn1_b = (const float*)d_in[12];
  const float* ffn2_w = (const float*)d_in[13];
  const float* ffn2_b = (const float*)d_in[14];
  float* out = (float*)d_out;

  char* ws = (char*)d_ws;
  const size_t MB = 1u << 20;
  float*          x1    = (float*)(ws);                    // 32MB (GEMM1 out)
  unsigned short* ybf   = (unsigned short*)(ws + 32*MB);   // 16MB; reused as xn2
  unsigned short* hdn   = (unsigned short*)(ws + 48*MB);   // 64MB
  unsigned short* w1b   = (unsigned short*)(ws + 112*MB);  // 2MB
  unsigned short* w2b   = (unsigned short*)(ws + 114*MB);  // 8MB
  unsigned short* w3b   = (unsigned short*)(ws + 122*MB);  // 8MB
  float*          hend  = (float*)(ws + 130*MB);           // 8MB
  float*          carry = (float*)(ws + 138*MB);           // 8MB
  float2*         stats = (float2*)(ws + 146*MB);          // 64KB

  // weights -> bf16
  cvt_bf16<<<(D_MODEL*D_MODEL/4)/256, 256, 0, stream>>>(out_w,  w1b, D_MODEL*D_MODEL/4);
  cvt_bf16<<<(H_FFN*D_MODEL/4)/256,  256, 0, stream>>>(ffn1_w, w2b, H_FFN*D_MODEL/4);
  cvt_bf16<<<(H_FFN*D_MODEL/4)/256,  256, 0, stream>>>(ffn2_w, w3b, H_FFN*D_MODEL/4);

  // LN1 stats (normalize fused into scan)
  ln_stats<<<M_ROWS, 256, 0, stream>>>(x, stats);

  // SSM scan -> ybf = silu(y) bf16
  dim3 gscan(D_MODEL/256, NCHUNK, BATCH);
  scan_phase1<<<gscan, 256, 0, stream>>>(x, stats, ln_w, ln_b, A_log, B_mat, hend);
  scan_phase2<<<(BATCH*D_MODEL*N_STATE)/256, 256, 0, stream>>>(A_log, hend, carry);
  scan_phase3<<<gscan, 256, 0, stream>>>(x, stats, ln_w, ln_b, A_log, B_mat, C_mat,
                                         D_vec, carry, ybf);

  // GEMM1: x1 = x + silu_y @ out_w^T + out_b   (grid 256)
  gemm_8p<128, 0, true, float><<<dim3((M_ROWS/256)*(D_MODEL/128)), 512, 0, stream>>>(
      ybf, w1b, out_b, x, x1, M_ROWS, D_MODEL, D_MODEL);

  // LN2: xn2 = LN(x1) bf16 (into ybf buffer)
  ln_kernel_bf16<<<M_ROWS, 256, 0, stream>>>(x1, ln2_w, ln2_b, ybf);

  // GEMM2: hdn = gelu(xn2 @ ffn1^T + ffn1_b) bf16  (grid 512)
  gemm_8p<256, 1, false, unsigned short><<<dim3((M_ROWS/256)*(H_FFN/256)), 512, 0, stream>>>(
      ybf, w2b, ffn1_b, nullptr, hdn, M_ROWS, H_FFN, D_MODEL);

  // GEMM3: out = x1 + hdn @ ffn2^T + ffn2_b (grid 256)
  gemm_8p<128, 0, true, float><<<dim3((M_ROWS/256)*(D_MODEL/128)), 512, 0, stream>>>(
      hdn, w3b, ffn2_b, x1, out, M_ROWS, D_MODEL, H_FFN);
}